// Round 1
// baseline (177.437 us; speedup 1.0000x reference)
//
#include <hip/hip_runtime.h>
#include <hip/hip_bf16.h>

// Problem constants (from reference setup_inputs)
#define B_  16
#define C_  64
#define HW_ 65536   // 256*256

// ---------------------------------------------------------------------------
// Kernel 1: x_node[b,c] = mean over H*W of x[b,c,:,:]
// grid = B*C blocks, 256 threads; float4 loads (64 per thread)
// ---------------------------------------------------------------------------
__global__ __launch_bounds__(256) void k_reduce_mean(
    const float* __restrict__ x, float* __restrict__ x_node) {
    int bc  = blockIdx.x;                    // 0..1023  (b*64 + c)
    int tid = threadIdx.x;                   // 0..255
    const float4* p4 = (const float4*)(x + (size_t)bc * HW_);

    float s = 0.f;
#pragma unroll
    for (int i = 0; i < 64; ++i) {
        float4 v = p4[tid + 256 * i];
        s += (v.x + v.y) + (v.z + v.w);
    }
    // wave (64-lane) reduce
#pragma unroll
    for (int off = 32; off; off >>= 1) s += __shfl_down(s, off, 64);

    __shared__ float ls[4];
    int wid = tid >> 6, lane = tid & 63;
    if (lane == 0) ls[wid] = s;
    __syncthreads();
    if (tid == 0) {
        float t = (ls[0] + ls[1]) + (ls[2] + ls[3]);
        x_node[bc] = t * (1.0f / (float)HW_);
    }
}

// ---------------------------------------------------------------------------
// Kernel 2: tiny GCN math ->  w_eff[b,c], bias_eff[b]
//   h[b,n]   = sum_c x_node[b,c]*g1_w[n,c] + g1_b[n]
//   z1[b,n]  = h*g2_w + g2_b
//   w_eff[b,c]  = sum_n z1[b,n]*theta_w[n,c]
//   bias_eff[b] = sum_n z1[b,n]*theta_b[n]
// one block, B*C = 1024 threads
// ---------------------------------------------------------------------------
__global__ __launch_bounds__(1024) void k_small(
    const float* __restrict__ x_node,
    const float* __restrict__ theta_w, const float* __restrict__ theta_b,
    const float* __restrict__ g1_w,    const float* __restrict__ g1_b,
    const float* __restrict__ g2_w,    const float* __restrict__ g2_b,
    float* __restrict__ w_eff, float* __restrict__ bias_eff) {
    int t = threadIdx.x;
    int b = t >> 6, n = t & 63;

    __shared__ float z1s[B_][C_];
    float h = g1_b[n];
#pragma unroll
    for (int c = 0; c < C_; ++c) h += x_node[b * C_ + c] * g1_w[n * C_ + c];
    float z1 = h * g2_w[0] + g2_b[0];
    z1s[b][n] = z1;
    __syncthreads();

    int c = n;
    float w = 0.f;
#pragma unroll
    for (int nn = 0; nn < C_; ++nn) w += z1s[b][nn] * theta_w[nn * C_ + c];
    w_eff[b * C_ + c] = w;

    if (c == 0) {
        float bb = 0.f;
#pragma unroll
        for (int nn = 0; nn < C_; ++nn) bb += z1s[b][nn] * theta_b[nn];
        bias_eff[b] = bb;
    }
}

// ---------------------------------------------------------------------------
// Kernel 3: fused y + phi + tanh.  One pixel per thread; all 64 channel
// values held in registers (read x once, write out once).
//   y[p]        = bias_eff[b] + sum_c w_eff[b,c]*x[b,c,p]
//   out[b,c,p]  = tanh(y[p]*phi_w[c] + phi_b[c] + x[b,c,p])
// grid = B * (HW/256) blocks, 256 threads
// ---------------------------------------------------------------------------
__global__ __launch_bounds__(256) void k_fused_out(
    const float* __restrict__ x,
    const float* __restrict__ w_eff, const float* __restrict__ bias_eff,
    const float* __restrict__ phi_w, const float* __restrict__ phi_b,
    float* __restrict__ out) {
    int blk   = blockIdx.x;
    int b     = blk >> 8;        // HW/256 = 256 chunks per batch
    int chunk = blk & 255;
    int p     = chunk * 256 + threadIdx.x;

    __shared__ float wsh[C_], pw[C_], pb[C_];
    if (threadIdx.x < C_) {
        wsh[threadIdx.x] = w_eff[b * C_ + threadIdx.x];
        pw[threadIdx.x]  = phi_w[threadIdx.x];
        pb[threadIdx.x]  = phi_b[threadIdx.x];
    }
    __syncthreads();

    const float* px = x + (size_t)b * C_ * HW_ + p;
    float xs[C_];
    float y = bias_eff[b];
#pragma unroll
    for (int c = 0; c < C_; ++c) {
        xs[c] = px[(size_t)c * HW_];
        y += wsh[c] * xs[c];
    }

    float* po = out + (size_t)b * C_ * HW_ + p;
#pragma unroll
    for (int c = 0; c < C_; ++c) {
        po[(size_t)c * HW_] = tanhf(y * pw[c] + pb[c] + xs[c]);
    }
}

// ---------------------------------------------------------------------------
extern "C" void kernel_launch(void* const* d_in, const int* in_sizes, int n_in,
                              void* d_out, int out_size, void* d_ws, size_t ws_size,
                              hipStream_t stream) {
    const float* x       = (const float*)d_in[0];
    const float* theta_w = (const float*)d_in[1];
    const float* theta_b = (const float*)d_in[2];
    const float* g1_w    = (const float*)d_in[3];
    const float* g1_b    = (const float*)d_in[4];
    const float* g2_w    = (const float*)d_in[5];
    const float* g2_b    = (const float*)d_in[6];
    const float* phi_w   = (const float*)d_in[7];
    const float* phi_b   = (const float*)d_in[8];
    float* out = (float*)d_out;

    float* x_node   = (float*)d_ws;                 // B*C floats
    float* w_eff    = x_node + B_ * C_;             // B*C floats
    float* bias_eff = w_eff + B_ * C_;              // B floats

    k_reduce_mean<<<B_ * C_, 256, 0, stream>>>(x, x_node);
    k_small<<<1, B_ * C_, 0, stream>>>(x_node, theta_w, theta_b, g1_w, g1_b,
                                       g2_w, g2_b, w_eff, bias_eff);
    k_fused_out<<<B_ * (HW_ / 256), 256, 0, stream>>>(x, w_eff, bias_eff,
                                                      phi_w, phi_b, out);
}

// Round 2
// 136.949 us; speedup vs baseline: 1.2956x; 1.2956x over previous
//
#include <hip/hip_runtime.h>
#include <hip/hip_bf16.h>

// Problem constants (from reference setup_inputs)
#define B_   16
#define C_   64
#define HW_  65536   // 256*256
#define TILE 128     // pixels per block in fused kernel

typedef float f4_t __attribute__((ext_vector_type(4)));

// fast branch-free tanh: (e^2z - 1)/(e^2z + 1), clamped
__device__ __forceinline__ float fast_tanh(float z) {
    z = fminf(fmaxf(z, -15.f), 15.f);
    float e = __expf(2.f * z);
    return 1.f - 2.f * __builtin_amdgcn_rcpf(e + 1.f);
}

// ---------------------------------------------------------------------------
// Kernel 1: x_node[b,c] = mean over H*W of x[b,c,:,:]
// grid = B*C blocks, 256 threads; float4 loads (64 per thread)
// ---------------------------------------------------------------------------
__global__ __launch_bounds__(256) void k_reduce_mean(
    const float* __restrict__ x, float* __restrict__ x_node) {
    int bc  = blockIdx.x;                    // 0..1023  (b*64 + c)
    int tid = threadIdx.x;                   // 0..255
    const float4* p4 = (const float4*)(x + (size_t)bc * HW_);

    float s = 0.f;
#pragma unroll
    for (int i = 0; i < 64; ++i) {
        float4 v = p4[tid + 256 * i];
        s += (v.x + v.y) + (v.z + v.w);
    }
#pragma unroll
    for (int off = 32; off; off >>= 1) s += __shfl_down(s, off, 64);

    __shared__ float ls[4];
    int wid = tid >> 6, lane = tid & 63;
    if (lane == 0) ls[wid] = s;
    __syncthreads();
    if (tid == 0) {
        float t = (ls[0] + ls[1]) + (ls[2] + ls[3]);
        x_node[bc] = t * (1.0f / (float)HW_);
    }
}

// ---------------------------------------------------------------------------
// Kernel 2: tiny GCN math ->  w_eff[b,c], bias_eff[b]
// ---------------------------------------------------------------------------
__global__ __launch_bounds__(1024) void k_small(
    const float* __restrict__ x_node,
    const float* __restrict__ theta_w, const float* __restrict__ theta_b,
    const float* __restrict__ g1_w,    const float* __restrict__ g1_b,
    const float* __restrict__ g2_w,    const float* __restrict__ g2_b,
    float* __restrict__ w_eff, float* __restrict__ bias_eff) {
    int t = threadIdx.x;
    int b = t >> 6, n = t & 63;

    __shared__ float z1s[B_][C_];
    float h = g1_b[n];
#pragma unroll
    for (int c = 0; c < C_; ++c) h += x_node[b * C_ + c] * g1_w[n * C_ + c];
    float z1 = h * g2_w[0] + g2_b[0];
    z1s[b][n] = z1;
    __syncthreads();

    int c = n;
    float w = 0.f;
#pragma unroll
    for (int nn = 0; nn < C_; ++nn) w += z1s[b][nn] * theta_w[nn * C_ + c];
    w_eff[b * C_ + c] = w;

    if (c == 0) {
        float bb = 0.f;
#pragma unroll
        for (int nn = 0; nn < C_; ++nn) bb += z1s[b][nn] * theta_b[nn];
        bias_eff[b] = bb;
    }
}

// ---------------------------------------------------------------------------
// Kernel 3: fused y + phi + tanh, LDS-staged 64x128 tile.
// All global loads/stores are float4 (1 KiB/wave-instr). Non-temporal out
// stores keep x resident in L3 for the second read.
//   y[p]        = bias_eff[b] + sum_c w_eff[b,c]*x[b,c,p]
//   out[b,c,p]  = fast_tanh(y[p]*phi_w[c] + phi_b[c] + x[b,c,p])
// grid = B * (HW/TILE) = 8192 blocks, 256 threads
// ---------------------------------------------------------------------------
__global__ __launch_bounds__(256) void k_fused_out(
    const float* __restrict__ x,
    const float* __restrict__ w_eff, const float* __restrict__ bias_eff,
    const float* __restrict__ phi_w, const float* __restrict__ phi_b,
    float* __restrict__ out) {
    __shared__ float tile[C_][TILE];   // 32 KiB
    __shared__ float ys[TILE];
    __shared__ float wsh[C_], pw[C_], pb[C_];

    int t  = threadIdx.x;
    int b  = blockIdx.x >> 9;          // HW/TILE = 512 tiles per batch
    int ti = blockIdx.x & 511;
    int p0 = ti * TILE;

    if (t < C_) {
        wsh[t] = w_eff[b * C_ + t];
        pw[t]  = phi_w[t];
        pb[t]  = phi_b[t];
    }

    const float* xb = x + (size_t)b * C_ * HW_ + p0;
    // load 64x128 tile: 2048 float4s, 8 iterations of 256 threads
#pragma unroll
    for (int i = 0; i < 8; ++i) {
        int f = i * 256 + t;
        int c = f >> 5;                // TILE/4 = 32 float4 per channel row
        int j = f & 31;
        float4 v = *(const float4*)(xb + (size_t)c * HW_ + 4 * j);
        *(float4*)&tile[c][4 * j] = v;
    }
    __syncthreads();

    if (t < TILE) {
        float y = bias_eff[b];
#pragma unroll
        for (int c = 0; c < C_; ++c) y += wsh[c] * tile[c][t];
        ys[t] = y;
    }
    __syncthreads();

    float* ob = out + (size_t)b * C_ * HW_ + p0;
#pragma unroll
    for (int i = 0; i < 8; ++i) {
        int f = i * 256 + t;
        int c = f >> 5;
        int j = f & 31;
        float4 v  = *(float4*)&tile[c][4 * j];
        float4 yv = *(float4*)&ys[4 * j];
        float a = pw[c], d = pb[c];
        f4_t r;
        r.x = fast_tanh(yv.x * a + d + v.x);
        r.y = fast_tanh(yv.y * a + d + v.y);
        r.z = fast_tanh(yv.z * a + d + v.z);
        r.w = fast_tanh(yv.w * a + d + v.w);
        __builtin_nontemporal_store(r, (f4_t*)(ob + (size_t)c * HW_ + 4 * j));
    }
}

// ---------------------------------------------------------------------------
extern "C" void kernel_launch(void* const* d_in, const int* in_sizes, int n_in,
                              void* d_out, int out_size, void* d_ws, size_t ws_size,
                              hipStream_t stream) {
    const float* x       = (const float*)d_in[0];
    const float* theta_w = (const float*)d_in[1];
    const float* theta_b = (const float*)d_in[2];
    const float* g1_w    = (const float*)d_in[3];
    const float* g1_b    = (const float*)d_in[4];
    const float* g2_w    = (const float*)d_in[5];
    const float* g2_b    = (const float*)d_in[6];
    const float* phi_w   = (const float*)d_in[7];
    const float* phi_b   = (const float*)d_in[8];
    float* out = (float*)d_out;

    float* x_node   = (float*)d_ws;                 // B*C floats
    float* w_eff    = x_node + B_ * C_;             // B*C floats
    float* bias_eff = w_eff + B_ * C_;              // B floats

    k_reduce_mean<<<B_ * C_, 256, 0, stream>>>(x, x_node);
    k_small<<<1, B_ * C_, 0, stream>>>(x_node, theta_w, theta_b, g1_w, g1_b,
                                       g2_w, g2_b, w_eff, bias_eff);
    k_fused_out<<<B_ * (HW_ / TILE), 256, 0, stream>>>(x, w_eff, bias_eff,
                                                       phi_w, phi_b, out);
}